// Round 1
// baseline (345.957 us; speedup 1.0000x reference)
//
#include <hip/hip_runtime.h>

// SimpleMovingAverage: history (64, 336, 862, 3) f32.
// window = last 12 timesteps; 336 recursive-mean steps; out (64, 336, 862, 3).
// 64*862*3 = 165,504 independent scalar recurrences of length 336.

#define Q 12
#define IN_LEN 336
#define OUT_LEN 336
#define NB 64
#define SC (862 * 3)   // contiguous (series, channel) extent per (b, t)

__global__ __launch_bounds__(256) void
SimpleMovingAverage_22144851378808_kernel(const float* __restrict__ in,
                                          float* __restrict__ out) {
    const int tid = blockIdx.x * blockDim.x + threadIdx.x;
    if (tid >= NB * SC) return;
    const int b  = tid / SC;
    const int sc = tid - b * SC;

    // Load the last Q timesteps of this series (coalesced: consecutive tid ->
    // consecutive addresses at each k).
    const float* inp = in + ((size_t)(b * IN_LEN + (IN_LEN - Q)) * SC + sc);
    float w[Q];
#pragma unroll
    for (int k = 0; k < Q; ++k) w[k] = inp[(size_t)k * SC];

    float sum = 0.f;
#pragma unroll
    for (int k = 0; k < Q; ++k) sum += w[k];

    float* op = out + ((size_t)b * OUT_LEN * SC + sc);
    const float inv = 1.0f / (float)Q;

    // 336 = 28 * 12: unroll the circular buffer in blocks of Q so the
    // window index is compile-time constant (stays in registers).
    for (int t = 0; t < OUT_LEN; t += Q) {
#pragma unroll
        for (int j = 0; j < Q; ++j) {
            const float m = sum * inv;
            sum += m - w[j];     // drop oldest, append mean
            w[j] = m;
            op[(size_t)(t + j) * SC] = m;   // coalesced: wave writes 256B contiguous
        }
        // Re-anchor the running sum every Q steps to kill FP drift.
        float s = 0.f;
#pragma unroll
        for (int k = 0; k < Q; ++k) s += w[k];
        sum = s;
    }
}

extern "C" void kernel_launch(void* const* d_in, const int* in_sizes, int n_in,
                              void* d_out, int out_size, void* d_ws, size_t ws_size,
                              hipStream_t stream) {
    const float* in = (const float*)d_in[0];
    float* out = (float*)d_out;
    const int n_series = NB * SC;                 // 165,504
    const int block = 256;
    const int grid = (n_series + block - 1) / block;  // 647
    SimpleMovingAverage_22144851378808_kernel<<<grid, block, 0, stream>>>(in, out);
}